// Round 12
// baseline (368.635 us; speedup 1.0000x reference)
//
#include <hip/hip_runtime.h>
#include <hip/hip_bf16.h>

#define F1 128
#define F2 256
#define F3 128
#define CAP 64

// bucket geometry: 256 nodes per bucket
#define NB1D 391   // ceil(100000/256) dst1 buckets
#define NB2D 196   // ceil(50000/256)  dst2 buckets
#define NB1S 782   // ceil(200000/256) src1 buckets
#define NB2S 391   // ceil(100000/256) src2 buckets
#define CAPD 4608  // dst-bucket capacity (mean ~4092, sd ~64 -> 8 sigma)
#define CAPS 2432  // src-bucket capacity (mean ~2046, sd ~45 -> 8.5 sigma)
// gcnt layout offsets
#define GD1 0
#define GD2 391
#define GS1 587
#define GS2 1369

#define YPAD 100096  // gemm12 writes zero rows [N1, YPAD); row N1 = sentinel

typedef __attribute__((ext_vector_type(8))) short bf16x8;
typedef __attribute__((ext_vector_type(4))) float f32x4;
typedef __attribute__((ext_vector_type(2))) float f32x2;
typedef __attribute__((ext_vector_type(4))) unsigned int u32x4;

__device__ inline float bf2f(unsigned short u) {
    return __uint_as_float(((unsigned int)u) << 16);
}
__device__ inline unsigned short f2bf(float f) {
    __hip_bfloat16 b = __float2bfloat16(f);
    return *reinterpret_cast<unsigned short*>(&b);
}
__device__ inline unsigned int pack2(float lo, float hi) {
    return ((unsigned int)f2bf(hi) << 16) | f2bf(lo);
}
__device__ inline float rsdeg(int c) {
    return rsqrtf((float)(c < 1 ? 1 : c));
}

// unpack a u32 holding 2 bf16 into an f32x2 {lo, hi}
#define UPK(w) ((f32x2){__uint_as_float((unsigned int)(w) << 16),     \
                        __uint_as_float((unsigned int)(w) & 0xffff0000u)})

// packed accumulate of one gathered row scaled by cc (f32x2 splat) -> v_pk_fma
#define ACC_ROW2(u, cc)                       \
    av[0] = UPK(u.x) * cc + av[0];            \
    av[1] = UPK(u.y) * cc + av[1];            \
    av[2] = UPK(u.z) * cc + av[2];            \
    av[3] = UPK(u.w) * cc + av[3];

// packed unconditional accumulate (sentinel-row masking) -> v_pk_add
#define ACC_ROW_ADD2(u)                       \
    av[0] += UPK(u.x);                        \
    av[1] += UPK(u.y);                        \
    av[2] += UPK(u.z);                        \
    av[3] += UPK(u.w);

// ---------------------------------------------------------------- kernel A (1024 thr)
// block ranges: [0,A1) L1 edge scatter (8192 edges), [A1,A1+A2) L2,
// [+B3) x fp32->bf16 (8192 elems/block), [+64) weight permutes (32 blocks each).
// Edge blocks use LDS-staged bucket-sorted flush: wave-coalesced run writes.
// NOTE (round-7 lesson): no direct-CSR scatter — single 4B writes over a wide
// region dirty a full line each (~64x write amp). NOTE (round-9 lesson): no
// per-edge global atomics on counter tables — cross-XCD line migration.
// LDS pre-aggregation before global traffic is the invariant.
__global__ __launch_bounds__(1024) void scatter_build(
    const int* __restrict__ src1, const int* __restrict__ dst1,
    const int* __restrict__ src2, const int* __restrict__ dst2,
    const float* __restrict__ x, const float* __restrict__ W1,
    const float* __restrict__ W2, int* __restrict__ gcnt,
    unsigned int* __restrict__ bkt_d1, unsigned int* __restrict__ bkt_d2,
    unsigned char* __restrict__ bkt_s1, unsigned char* __restrict__ bkt_s2,
    unsigned int* __restrict__ xn, unsigned short* __restrict__ Bp1,
    unsigned short* __restrict__ Bp2, int E1, int E2, int A1, int A2, int B3) {
    __shared__ int hist[800];            // counts (max NBs = 782)
    __shared__ int scanA[800], scanB[800];
    __shared__ unsigned int stg[8192];   // bucket-sorted staged entries
    __shared__ unsigned short bmap[8192];// stage index -> bucket id
    int b = blockIdx.x, t = threadIdx.x;

    if (b < A1 + A2) {
        const int L1 = (b < A1);
        const int* __restrict__ src = L1 ? src1 : src2;
        const int* __restrict__ dst = L1 ? dst1 : dst2;
        const int E = L1 ? E1 : E2;
        const int NBd = L1 ? NB1D : NB2D;
        const int NBs = L1 ? NB1S : NB2S;
        int* gd = gcnt + (L1 ? GD1 : GD2);
        int* gs = gcnt + (L1 ? GS1 : GS2);
        unsigned int* bd = L1 ? bkt_d1 : bkt_d2;
        unsigned char* bs = L1 ? bkt_s1 : bkt_s2;
        int e0 = (L1 ? b : b - A1) * 8192;
        // load edges to registers once
        int se[8], de[8];
#pragma unroll
        for (int k = 0; k < 8; ++k) {
            int e = e0 + k * 1024 + t;
            se[k] = -1;
            de[k] = -1;
            if (e < E) {
                se[k] = src[e];
                de[k] = dst[e];
            }
        }

        // ================= phase A: dst buckets (value = s<<8 | d&255) ==
        for (int i = t; i < NBd; i += 1024) hist[i] = 0;
        __syncthreads();
#pragma unroll
        for (int k = 0; k < 8; ++k)
            if (de[k] >= 0) atomicAdd(&hist[de[k] >> 8], 1);
        __syncthreads();
        // inclusive scan (Hillis-Steele ping-pong)
        {
            int* sa = scanA;
            int* sb = scanB;
            for (int i = t; i < NBd; i += 1024) sa[i] = hist[i];
            __syncthreads();
            for (int off = 1; off < NBd; off <<= 1) {
                for (int i = t; i < NBd; i += 1024) {
                    int v = sa[i];
                    if (i >= off) v += sa[i - off];
                    sb[i] = v;
                }
                __syncthreads();
                int* tp = sa; sa = sb; sb = tp;
            }
            // sa = inclusive scan; sb = scratch -> stage cursors (excl starts)
            for (int i = t; i < NBd; i += 1024) sb[i] = sa[i] - hist[i];
            __syncthreads();
#pragma unroll
            for (int k = 0; k < 8; ++k) {
                if (de[k] >= 0) {
                    int bk = de[k] >> 8;
                    int p = atomicAdd(&sb[bk], 1);
                    stg[p] = ((unsigned int)se[k] << 8) | (de[k] & 255);
                    bmap[p] = (unsigned short)bk;
                }
            }
            __syncthreads();
            // reserve global runs; sb[i] := gbase_i - lstart_i
            for (int i = t; i < NBd; i += 1024) {
                int c = hist[i];
                int g = c ? atomicAdd(&gd[i], c) : 0;
                sb[i] = g - (sa[i] - c);
            }
            __syncthreads();
            int total = sa[NBd - 1];
            // coalesced flush: consecutive i -> consecutive addresses per run
            for (int i = t; i < total; i += 1024) {
                int bk = bmap[i];
                int gpos = sb[bk] + i;
                if (gpos < CAPD) bd[(size_t)bk * CAPD + gpos] = stg[i];
            }
        }
        __syncthreads();

        // ================= phase B: src buckets (value = s&255, byte) ====
        for (int i = t; i < NBs; i += 1024) hist[i] = 0;
        __syncthreads();
#pragma unroll
        for (int k = 0; k < 8; ++k)
            if (se[k] >= 0) atomicAdd(&hist[se[k] >> 8], 1);
        __syncthreads();
        {
            int* sa = scanA;
            int* sb = scanB;
            for (int i = t; i < NBs; i += 1024) sa[i] = hist[i];
            __syncthreads();
            for (int off = 1; off < NBs; off <<= 1) {
                for (int i = t; i < NBs; i += 1024) {
                    int v = sa[i];
                    if (i >= off) v += sa[i - off];
                    sb[i] = v;
                }
                __syncthreads();
                int* tp = sa; sa = sb; sb = tp;
            }
            for (int i = t; i < NBs; i += 1024) sb[i] = sa[i] - hist[i];
            __syncthreads();
#pragma unroll
            for (int k = 0; k < 8; ++k) {
                if (se[k] >= 0) {
                    int bk = se[k] >> 8;
                    int p = atomicAdd(&sb[bk], 1);
                    stg[p] = (unsigned int)(se[k] & 255);
                    bmap[p] = (unsigned short)bk;
                }
            }
            __syncthreads();
            for (int i = t; i < NBs; i += 1024) {
                int c = hist[i];
                int g = c ? atomicAdd(&gs[i], c) : 0;
                sb[i] = g - (sa[i] - c);
            }
            __syncthreads();
            int total = sa[NBs - 1];
            for (int i = t; i < total; i += 1024) {
                int bk = bmap[i];
                int gpos = sb[bk] + i;
                if (gpos < CAPS) bs[(size_t)bk * CAPS + gpos] = (unsigned char)stg[i];
            }
        }
    } else if (b < A1 + A2 + B3) {
        // x fp32 -> bf16, 8 elems/thread, exact thread count. NT loads keep
        // the read-once x stream out of L2.
        size_t tid = (size_t)(b - A1 - A2) * 1024 + t;
        const f32x4* xp = (const f32x4*)x;
        f32x4 a = __builtin_nontemporal_load(xp + tid * 2);
        f32x4 c = __builtin_nontemporal_load(xp + tid * 2 + 1);
        u32x4 o;
        o.x = pack2(a.x, a.y);
        o.y = pack2(a.z, a.w);
        o.z = pack2(c.x, c.y);
        o.w = pack2(c.z, c.w);
        ((u32x4*)xn)[tid] = o;
    } else {
        int w = b - (A1 + A2 + B3);          // 0..63; 32 blocks per weight
        int which = w >> 5;
        const float* W = which ? W2 : W1;
        unsigned short* out = which ? Bp2 : Bp1;
        int N = which ? F3 : F2;
        int idx = (w & 31) * 1024 + t;       // both weights have 32768 elems
        int k = idx / N, n = idx % N;
        unsigned short v = f2bf(W[idx]);
        int kt = k >> 5, q = (k >> 3) & 3, j = k & 7;
        int nt = n >> 4, lane = q * 16 + (n & 15);
        int NT = N >> 4;
        out[(((kt * NT + nt) * 64 + lane) << 3) + j] = v;
    }
}

// ---------------------------------------------------------------- kernel B (512 thr)
// one block per bucket.
// dst-buckets: stage bucket in LDS -> hist -> 256-scan -> COMPACT csr in LDS
// -> coalesced flush + off/cnt/rs_in. Compact layout: adjacent nodes' edge
// lists share cache lines (mean 64 B/list vs a private 256 B padded region),
// cutting agg-side csr fetch ~4x and making bucket writes dense sequential.
// src-buckets: degree histogram -> rs_out (unchanged).
__global__ __launch_bounds__(512) void bucket_build(
    const int* __restrict__ gcnt,
    const unsigned int* __restrict__ bkt_d1, const unsigned int* __restrict__ bkt_d2,
    const unsigned char* __restrict__ bkt_s1, const unsigned char* __restrict__ bkt_s2,
    int* __restrict__ csrc1, int* __restrict__ off_in1, int* __restrict__ cnt_in1,
    float* __restrict__ rs_in1,
    int* __restrict__ csrc2, int* __restrict__ off_in2, int* __restrict__ cnt_in2,
    float* __restrict__ rs_in2,
    float* __restrict__ rs_out1, float* __restrict__ rs_out2) {
    __shared__ unsigned int stage[CAPD];   // 18.4 KB bucket staging
    __shared__ int ccsr[CAPD];             // 18.4 KB compact csr
    __shared__ int hist[256], offs[256], cur[256];
    int b = blockIdx.x, t = threadIdx.x;

    if (b < NB1D + NB2D) {
        const int L1 = (b < NB1D);
        int bb = L1 ? b : b - NB1D;
        const unsigned int* bkt = L1 ? bkt_d1 : bkt_d2;
        int* csrc = L1 ? csrc1 : csrc2;
        int* off_in = L1 ? off_in1 : off_in2;
        int* cnt_in = L1 ? cnt_in1 : cnt_in2;
        float* rs_in = L1 ? rs_in1 : rs_in2;
        int Nd = L1 ? 100000 : 50000;
        int n = gcnt[(L1 ? GD1 : GD2) + bb];
        if (n > CAPD) n = CAPD;
        size_t base = (size_t)bb * CAPD;
        if (t < 256) hist[t] = 0;
        // stage bucket to LDS (coalesced)
        for (int i = t; i < n; i += 512) stage[i] = bkt[base + i];
        __syncthreads();
        // count
        for (int i = t; i < n; i += 512) atomicAdd(&hist[stage[i] & 255], 1);
        __syncthreads();
        // inclusive scan of hist (256 entries, Hillis-Steele in LDS)
        if (t < 256) offs[t] = hist[t];
        __syncthreads();
        for (int o = 1; o < 256; o <<= 1) {
            int v = 0;
            if (t < 256) {
                v = offs[t];
                if (t >= o) v += offs[t - o];
            }
            __syncthreads();
            if (t < 256) offs[t] = v;
            __syncthreads();
        }
        // cursors = exclusive starts
        if (t < 256) cur[t] = offs[t] - hist[t];
        __syncthreads();
        // scatter into compact LDS csr
        for (int i = t; i < n; i += 512) {
            unsigned int v = stage[i];
            int p = atomicAdd(&cur[v & 255], 1);
            ccsr[p] = (int)(v >> 8);
        }
        __syncthreads();
        // coalesced flush of dense list
        for (int i = t; i < n; i += 512) csrc[base + i] = ccsr[i];
        // per-node outputs
        int node = bb * 256 + t;
        if (t < 256 && node < Nd) {
            int c = hist[t];
            cnt_in[node] = c < CAP ? c : CAP;
            off_in[node] = (int)base + (offs[t] - c);
            rs_in[node] = rsdeg(c);
        }
    } else {
        const int L1 = (b < NB1D + NB2D + NB1S);
        int bb = L1 ? b - (NB1D + NB2D) : b - (NB1D + NB2D + NB1S);
        const unsigned char* bkt = L1 ? bkt_s1 : bkt_s2;
        float* rs_out = L1 ? rs_out1 : rs_out2;
        int Ns = L1 ? 200000 : 100000;
        int n = gcnt[(L1 ? GS1 : GS2) + bb];
        if (n > CAPS) n = CAPS;
        size_t base = (size_t)bb * CAPS;
        if (t < 256) hist[t] = 0;
        __syncthreads();
        for (int i = t; i < n; i += 512) atomicAdd(&hist[bkt[base + i]], 1);
        __syncthreads();
        int node = bb * 256 + t;
        if (t < 256 && node < Ns) rs_out[node] = rsdeg(hist[t]);
    }
}

// ---------------------------------------------------------------- gather aggregation
// F=128 bf16 rows, one wave per dst row. eg = lane>>4 picks one of 4 edges per
// group, fs = lane&15 picks a 16B feature slot. 16 edges/iteration = 4
// independent u32x4 row-gathers (blend-BW ceiling on the X-gather itself).
// Compact csr: edge list read from csrc[off .. off+len) (shared cache lines).
__global__ __launch_bounds__(256) void agg128_kernel(
    const unsigned int* __restrict__ X, const int* __restrict__ csrc,
    const int* __restrict__ offv, const int* __restrict__ cnt,
    const float* __restrict__ rs_src, unsigned int* __restrict__ out, int ndst) {
    int wave = (int)((blockIdx.x * blockDim.x + threadIdx.x) >> 6);
    int lane = threadIdx.x & 63;
    if (wave >= ndst) return;
    int len = cnt[wave];
    int off = offv[wave];
    int sl = 0;
    float clv = 0.f;
    if (lane < len) {
        sl = csrc[off + lane];
        clv = rs_src[sl];
    }
    int eg = lane >> 4, fs = lane & 15;
    f32x2 av[4];
#pragma unroll
    for (int i = 0; i < 4; ++i) av[i] = (f32x2){0.f, 0.f};
    for (int j = 0; j < len; j += 16) {
        int jA = j + eg, jB = j + 4 + eg, jC = j + 8 + eg, jD = j + 12 + eg;
        int sA = __shfl(sl, jA);
        int sB = __shfl(sl, jB);
        int sC = __shfl(sl, jC);
        int sD = __shfl(sl, jD);
        float cA = __shfl(clv, jA);
        float cB = __shfl(clv, jB);
        float cC = __shfl(clv, jC);
        float cD = __shfl(clv, jD);
        u32x4 uA = *(const u32x4*)(X + (size_t)sA * 64 + (fs << 2));
        u32x4 uB = *(const u32x4*)(X + (size_t)sB * 64 + (fs << 2));
        u32x4 uC = *(const u32x4*)(X + (size_t)sC * 64 + (fs << 2));
        u32x4 uD = *(const u32x4*)(X + (size_t)sD * 64 + (fs << 2));
        f32x2 ccA = (f32x2){cA, cA};
        f32x2 ccB = (f32x2){cB, cB};
        f32x2 ccC = (f32x2){cC, cC};
        f32x2 ccD = (f32x2){cD, cD};
        ACC_ROW2(uA, ccA)
        ACC_ROW2(uB, ccB)
        ACC_ROW2(uC, ccC)
        ACC_ROW2(uD, ccD)
    }
#pragma unroll
    for (int i = 0; i < 4; ++i) {
        av[i].x += __shfl_xor(av[i].x, 16);
        av[i].x += __shfl_xor(av[i].x, 32);
        av[i].y += __shfl_xor(av[i].y, 16);
        av[i].y += __shfl_xor(av[i].y, 32);
    }
    if (eg == 0) {
        u32x4 o;
        o.x = pack2(av[0].x, av[0].y);
        o.y = pack2(av[1].x, av[1].y);
        o.z = pack2(av[2].x, av[2].y);
        o.w = pack2(av[3].x, av[3].y);
        *((u32x4*)(out + (size_t)wave * 64) + fs) = o;
    }
}

// ---------------------------------------------------------------- fused two-stage GEMM
// 512 threads = 8 waves x 16 rows = 128-row tile. B matrices staged in LDS.
// T14 split: Bp2 global loads issued with phase 0. Pad rows [M, YPAD) ZEROS.
__global__ __launch_bounds__(512) void gemm12(
    const unsigned short* __restrict__ A,    // agg [M,128] bf16
    const unsigned short* __restrict__ Bp1,  // W1 fragments (K=128,N=256)
    const unsigned short* __restrict__ Bp2,  // W2 fragments (K=256,N=128)
    const float* __restrict__ rs1, const float* __restrict__ rs2,
    const float* __restrict__ bias1,
    unsigned short* __restrict__ Y, int M) {
    __shared__ unsigned short Bs[32768];      // 64 KB, holds Bp1 then Bp2
    __shared__ unsigned short tmp[128][264];  // +8 pad, 67.6 KB
    int lane = threadIdx.x & 63, wid = threadIdx.x >> 6;
    int t = threadIdx.x;
    int row0 = blockIdx.x * 128 + wid * 16;
    int q = lane >> 4, col = lane & 15;

    // ---- phase 0: Bp1 -> LDS; Bp2 -> regs (issue-early, consume-late)
    u32x4 b2r[8];
#pragma unroll
    for (int i = 0; i < 8; ++i) {
        ((u32x4*)Bs)[i * 512 + t] = ((const u32x4*)Bp1)[i * 512 + t];
        b2r[i] = ((const u32x4*)Bp2)[i * 512 + t];
    }
    __syncthreads();

    // ---- stage 1: 16 rows x 256 cols per wave
    int mload = row0 + col;
    if (mload > M - 1) mload = M - 1;
    const unsigned short* Arow = A + (size_t)mload * F1 + q * 8;
    f32x4 acc[16];
#pragma unroll
    for (int i = 0; i < 16; ++i) acc[i] = (f32x4){0.f, 0.f, 0.f, 0.f};
#pragma unroll
    for (int kt = 0; kt < 4; ++kt) {
        bf16x8 a = *(const bf16x8*)(Arow + kt * 32);
#pragma unroll
        for (int nt = 0; nt < 16; ++nt) {
            bf16x8 bfr = *(const bf16x8*)(Bs + (((kt * 16 + nt) * 64 + lane) << 3));
            acc[nt] = __builtin_amdgcn_mfma_f32_16x16x32_bf16(a, bfr, acc[nt], 0, 0, 0);
        }
    }
#pragma unroll
    for (int r = 0; r < 4; ++r) {
        int lrow = wid * 16 + q * 4 + r;
        int m = row0 + q * 4 + r;
        int mc = m < M ? m : M - 1;
        float s1 = rs1[mc], s2 = rs2[mc];
#pragma unroll
        for (int nt = 0; nt < 16; ++nt) {
            float v = fmaxf(fmaf(acc[nt][r], s1, bias1[nt * 16 + col]), 0.f) * s2;
            tmp[lrow][nt * 16 + col] = f2bf(v);
        }
    }
    __syncthreads();

    // ---- phase 2: regs -> LDS (overwrite Bp1 region)
#pragma unroll
    for (int i = 0; i < 8; ++i)
        ((u32x4*)Bs)[i * 512 + t] = b2r[i];
    __syncthreads();

    // ---- stage 2: same 16 rows x 128 cols, K=256 from tmp
    f32x4 acc2[8];
#pragma unroll
    for (int i = 0; i < 8; ++i) acc2[i] = (f32x4){0.f, 0.f, 0.f, 0.f};
    const unsigned short* trow = &tmp[wid * 16 + col][q * 8];
#pragma unroll
    for (int kt = 0; kt < 8; ++kt) {
        bf16x8 a = *(const bf16x8*)(trow + kt * 32);
#pragma unroll
        for (int nt = 0; nt < 8; ++nt) {
            bf16x8 bfr = *(const bf16x8*)(Bs + (((kt * 8 + nt) * 64 + lane) << 3));
            acc2[nt] = __builtin_amdgcn_mfma_f32_16x16x32_bf16(a, bfr, acc2[nt], 0, 0, 0);
        }
    }
#pragma unroll
    for (int r = 0; r < 4; ++r) {
        int m = row0 + q * 4 + r;
        int live = m < M;
#pragma unroll
        for (int nt = 0; nt < 8; ++nt)
            Y[(size_t)m * F3 + nt * 16 + col] = live ? f2bf(acc2[nt][r]) : (unsigned short)0;
    }
}

// ---------------------------------------------------------------- final aggregation
// gather y rows (128 bf16), sum, out = relu(rs_in2[d]*sum + b2) -> fp32
// Compact csr + zero sentinel row (zrow) -> unconditional packed adds.
__global__ __launch_bounds__(256) void agg_final(
    const unsigned int* __restrict__ Yv, const int* __restrict__ csrc,
    const int* __restrict__ offv, const int* __restrict__ cnt,
    const float* __restrict__ rs_dst, const float* __restrict__ b2,
    float* __restrict__ out, int ndst, int zrow) {
    int wave = (int)((blockIdx.x * blockDim.x + threadIdx.x) >> 6);
    int lane = threadIdx.x & 63;
    if (wave >= ndst) return;
    int len = cnt[wave];
    int off = offv[wave];
    int sl = zrow;
    if (lane < len) sl = csrc[off + lane];
    int eg = lane >> 4, fs = lane & 15;
    f32x2 av[4];
#pragma unroll
    for (int i = 0; i < 4; ++i) av[i] = (f32x2){0.f, 0.f};
    for (int j = 0; j < len; j += 16) {
        int jA = j + eg, jB = j + 4 + eg, jC = j + 8 + eg, jD = j + 12 + eg;
        int sA = __shfl(sl, jA);
        int sB = __shfl(sl, jB);
        int sC = __shfl(sl, jC);
        int sD = __shfl(sl, jD);
        u32x4 uA = *(const u32x4*)(Yv + (size_t)sA * 64 + (fs << 2));
        u32x4 uB = *(const u32x4*)(Yv + (size_t)sB * 64 + (fs << 2));
        u32x4 uC = *(const u32x4*)(Yv + (size_t)sC * 64 + (fs << 2));
        u32x4 uD = *(const u32x4*)(Yv + (size_t)sD * 64 + (fs << 2));
        ACC_ROW_ADD2(uA)
        ACC_ROW_ADD2(uB)
        ACC_ROW_ADD2(uC)
        ACC_ROW_ADD2(uD)
    }
#pragma unroll
    for (int i = 0; i < 4; ++i) {
        av[i].x += __shfl_xor(av[i].x, 16);
        av[i].x += __shfl_xor(av[i].x, 32);
        av[i].y += __shfl_xor(av[i].y, 16);
        av[i].y += __shfl_xor(av[i].y, 32);
    }
    if (eg < 2) {
        float sc = rs_dst[wave];
        f32x4 bias = ((const f32x4*)b2)[(fs << 1) | eg];
        // static-index selection (no runtime-indexed register array)
        float v0 = eg ? av[2].x : av[0].x;
        float v1 = eg ? av[2].y : av[0].y;
        float v2 = eg ? av[3].x : av[1].x;
        float v3 = eg ? av[3].y : av[1].y;
        f32x4 o;
        o.x = fmaxf(fmaf(v0, sc, bias.x), 0.f);
        o.y = fmaxf(fmaf(v1, sc, bias.y), 0.f);
        o.z = fmaxf(fmaf(v2, sc, bias.z), 0.f);
        o.w = fmaxf(fmaf(v3, sc, bias.w), 0.f);
        __builtin_nontemporal_store(o, (f32x4*)out + (size_t)wave * 32 + (fs << 1) + eg);
    }
}

extern "C" void kernel_launch(void* const* d_in, const int* in_sizes, int n_in,
                              void* d_out, int out_size, void* d_ws, size_t ws_size,
                              hipStream_t stream) {
    const float* x  = (const float*)d_in[0];
    const float* W1 = (const float*)d_in[1];
    const float* b1 = (const float*)d_in[2];
    const float* W2 = (const float*)d_in[3];
    const float* b2 = (const float*)d_in[4];
    const int* src1 = (const int*)d_in[5];
    const int* dst1 = (const int*)d_in[6];
    const int* src2 = (const int*)d_in[7];
    const int* dst2 = (const int*)d_in[8];
    const int E1 = in_sizes[5], E2 = in_sizes[7];
    const int N0 = in_sizes[0] / F1;  // 200000
    const int N1 = 100000, N2 = 50000;

    // ---- workspace layout (all segment sizes multiples of 16 B)
    char* p = (char*)d_ws;
    int* gcnt = (int*)p; p += 2048 * 4;                          // 1760 used
    float* rs_out1 = (float*)p; p += (size_t)N0 * 4;
    float* rs_in1  = (float*)p; p += (size_t)N1 * 4;
    float* rs_out2 = (float*)p; p += (size_t)N1 * 4;
    float* rs_in2  = (float*)p; p += (size_t)N2 * 4;
    int* cnt_in1 = (int*)p; p += (size_t)N1 * 4;
    int* cnt_in2 = (int*)p; p += (size_t)N2 * 4;
    int* off_in1 = (int*)p; p += (size_t)N1 * 4;
    int* off_in2 = (int*)p; p += (size_t)N2 * 4;
    unsigned int* bkt_d1 = (unsigned int*)p; p += (size_t)NB1D * CAPD * 4;  // 7.2 MB
    unsigned int* bkt_d2 = (unsigned int*)p; p += (size_t)NB2D * CAPD * 4;  // 3.6 MB
    unsigned char* bkt_s1 = (unsigned char*)p; p += (size_t)NB1S * CAPS;    // 1.9 MB
    unsigned char* bkt_s2 = (unsigned char*)p; p += (size_t)NB2S * CAPS;    // 1.0 MB
    int* csrc1 = (int*)p; p += (size_t)NB1D * CAPD * 4;          // 7.2 MB compact
    int* csrc2 = (int*)p; p += (size_t)NB2D * CAPD * 4;          // 3.6 MB compact
    unsigned short* Bp1 = (unsigned short*)p; p += (size_t)F1 * F2 * 2;
    unsigned short* Bp2 = (unsigned short*)p; p += (size_t)F2 * F3 * 2;
    unsigned short* xn  = (unsigned short*)p; p += (size_t)N0 * F1 * 2;  // 51.2 MB
    unsigned short* agg = (unsigned short*)p; p += (size_t)N1 * F1 * 2;  // 25.6 MB
    // y aliases xn: xn dead after agg128; y (YPAD*F3 elems incl. zero pad rows)
    unsigned short* y = xn;

    (void)hipMemsetAsync(gcnt, 0, 2048 * 4, stream);

    // kernel A: bucket scatter (both layers) + x->bf16 + weight permutes
    int A1 = (E1 + 8191) / 8192;
    int A2 = (E2 + 8191) / 8192;
    int B3 = N0 * F1 / 8 / 1024;  // exact: 3125
    scatter_build<<<A1 + A2 + B3 + 64, 1024, 0, stream>>>(
        src1, dst1, src2, dst2, x, W1, W2, gcnt,
        bkt_d1, bkt_d2, bkt_s1, bkt_s2,
        (unsigned int*)xn, Bp1, Bp2, E1, E2, A1, A2, B3);

    // kernel B: per-bucket compact CSR + degree norms
    bucket_build<<<NB1D + NB2D + NB1S + NB2S, 512, 0, stream>>>(
        gcnt, bkt_d1, bkt_d2, bkt_s1, bkt_s2,
        csrc1, off_in1, cnt_in1, rs_in1,
        csrc2, off_in2, cnt_in2, rs_in2, rs_out1, rs_out2);

    // layer 1 aggregation (per-edge src norm, compact csr)
    agg128_kernel<<<(N1 + 3) / 4, 256, 0, stream>>>((const unsigned int*)xn, csrc1,
                                                    off_in1, cnt_in1, rs_out1,
                                                    (unsigned int*)agg, N1);

    // fused: hn = relu(rs_in1*(agg@W1)+b1)*rs_out2 ; y = hn@W2  (+ zero pads)
    gemm12<<<(N1 + 127) / 128, 512, 0, stream>>>(agg, Bp1, Bp2, rs_in1, rs_out2, b1, y, N1);

    // layer 2 aggregation + fused epilogue: out = relu(rs_in2*segsum(y) + b2)
    agg_final<<<(N2 + 3) / 4, 256, 0, stream>>>((const unsigned int*)y, csrc2,
                                                off_in2, cnt_in2, rs_in2, b2,
                                                (float*)d_out, N2, N1);
}

// Round 13
// 346.887 us; speedup vs baseline: 1.0627x; 1.0627x over previous
//
#include <hip/hip_runtime.h>
#include <hip/hip_bf16.h>

#define F1 128
#define F2 256
#define F3 128
#define CAP 64

// bucket geometry: 256 nodes per bucket
#define NB1D 391   // ceil(100000/256) dst1 buckets
#define NB2D 196   // ceil(50000/256)  dst2 buckets
#define NB1S 782   // ceil(200000/256) src1 buckets
#define NB2S 391   // ceil(100000/256) src2 buckets
#define CAPD 4608  // dst-bucket capacity (mean ~4092, sd ~64 -> 8 sigma)
#define CAPS 2432  // src-bucket capacity (mean ~2046, sd ~45 -> 8.5 sigma)
// gcnt layout offsets
#define GD1 0
#define GD2 391
#define GS1 587
#define GS2 1369

#define YPAD 100096  // gemm12 writes zero rows [N1, YPAD); row N1 = sentinel

typedef __attribute__((ext_vector_type(8))) short bf16x8;
typedef __attribute__((ext_vector_type(4))) float f32x4;
typedef __attribute__((ext_vector_type(2))) float f32x2;
typedef __attribute__((ext_vector_type(4))) unsigned int u32x4;

__device__ inline float bf2f(unsigned short u) {
    return __uint_as_float(((unsigned int)u) << 16);
}
__device__ inline unsigned short f2bf(float f) {
    __hip_bfloat16 b = __float2bfloat16(f);
    return *reinterpret_cast<unsigned short*>(&b);
}
__device__ inline unsigned int pack2(float lo, float hi) {
    return ((unsigned int)f2bf(hi) << 16) | f2bf(lo);
}

// unpack a u32 holding 2 bf16 into an f32x2 {lo, hi}: 2 VALU ops, no masks
// (lo: shift drops high bits; hi: and-mask IS the f32 bit pattern).
#define UPK(w) ((f32x2){__uint_as_float((unsigned int)(w) << 16),     \
                        __uint_as_float((unsigned int)(w) & 0xffff0000u)})

// packed accumulate of one gathered row scaled by cc (f32x2 splat) -> v_pk_fma
#define ACC_ROW2(u, cc)                       \
    av[0] = UPK(u.x) * cc + av[0];            \
    av[1] = UPK(u.y) * cc + av[1];            \
    av[2] = UPK(u.z) * cc + av[2];            \
    av[3] = UPK(u.w) * cc + av[3];

// packed unconditional accumulate (sentinel-row masking) -> v_pk_add
#define ACC_ROW_ADD2(u)                       \
    av[0] += UPK(u.x);                        \
    av[1] += UPK(u.y);                        \
    av[2] += UPK(u.z);                        \
    av[3] += UPK(u.w);

// ---------------------------------------------------------------- kernel A (1024 thr)
// block ranges: [0,A1) L1 edge scatter (8192 edges), [A1,A1+A2) L2,
// [+B3) x fp32->bf16 (8192 elems/block), [+64) weight permutes (32 blocks each).
// Edge blocks use LDS-staged bucket-sorted flush: wave-coalesced run writes.
// NOTE (round-7 lesson): do NOT replace with direct-CSR scatter — single 4B
// writes over the 38 MB csr region dirty a full line each (~64x write amp).
// NOTE (round-9 lesson): do NOT use per-edge global atomics on counter tables
// — cross-XCD line migration (75 MB WRITE for 1.2 MB of counters, 102 us).
// NOTE (round-12 lesson): padded 256B-aligned per-node csr beats compact
// (compact lists straddle lines shared across XCDs -> +100 MB re-fetch).
// LDS pre-aggregation before global traffic is the invariant.
__global__ __launch_bounds__(1024) void scatter_build(
    const int* __restrict__ src1, const int* __restrict__ dst1,
    const int* __restrict__ src2, const int* __restrict__ dst2,
    const float* __restrict__ x, const float* __restrict__ W1,
    const float* __restrict__ W2, int* __restrict__ gcnt,
    unsigned int* __restrict__ bkt_d1, unsigned int* __restrict__ bkt_d2,
    unsigned char* __restrict__ bkt_s1, unsigned char* __restrict__ bkt_s2,
    unsigned int* __restrict__ xn, unsigned short* __restrict__ Bp1,
    unsigned short* __restrict__ Bp2, int E1, int E2, int A1, int A2, int B3) {
    __shared__ int hist[800];            // counts (max NBs = 782)
    __shared__ int scanA[800], scanB[800];
    __shared__ unsigned int stg[8192];   // bucket-sorted staged entries
    __shared__ unsigned short bmap[8192];// stage index -> bucket id
    int b = blockIdx.x, t = threadIdx.x;

    if (b < A1 + A2) {
        const int L1 = (b < A1);
        const int* __restrict__ src = L1 ? src1 : src2;
        const int* __restrict__ dst = L1 ? dst1 : dst2;
        const int E = L1 ? E1 : E2;
        const int NBd = L1 ? NB1D : NB2D;
        const int NBs = L1 ? NB1S : NB2S;
        int* gd = gcnt + (L1 ? GD1 : GD2);
        int* gs = gcnt + (L1 ? GS1 : GS2);
        unsigned int* bd = L1 ? bkt_d1 : bkt_d2;
        unsigned char* bs = L1 ? bkt_s1 : bkt_s2;
        int e0 = (L1 ? b : b - A1) * 8192;
        // load edges to registers once
        int se[8], de[8];
#pragma unroll
        for (int k = 0; k < 8; ++k) {
            int e = e0 + k * 1024 + t;
            se[k] = -1;
            de[k] = -1;
            if (e < E) {
                se[k] = src[e];
                de[k] = dst[e];
            }
        }

        // ================= phase A: dst buckets (value = s<<8 | d&255) ==
        for (int i = t; i < NBd; i += 1024) hist[i] = 0;
        __syncthreads();
#pragma unroll
        for (int k = 0; k < 8; ++k)
            if (de[k] >= 0) atomicAdd(&hist[de[k] >> 8], 1);
        __syncthreads();
        // inclusive scan (Hillis-Steele ping-pong)
        {
            int* sa = scanA;
            int* sb = scanB;
            for (int i = t; i < NBd; i += 1024) sa[i] = hist[i];
            __syncthreads();
            for (int off = 1; off < NBd; off <<= 1) {
                for (int i = t; i < NBd; i += 1024) {
                    int v = sa[i];
                    if (i >= off) v += sa[i - off];
                    sb[i] = v;
                }
                __syncthreads();
                int* tp = sa; sa = sb; sb = tp;
            }
            // sa = inclusive scan; sb = scratch -> stage cursors (excl starts)
            for (int i = t; i < NBd; i += 1024) sb[i] = sa[i] - hist[i];
            __syncthreads();
#pragma unroll
            for (int k = 0; k < 8; ++k) {
                if (de[k] >= 0) {
                    int bk = de[k] >> 8;
                    int p = atomicAdd(&sb[bk], 1);
                    stg[p] = ((unsigned int)se[k] << 8) | (de[k] & 255);
                    bmap[p] = (unsigned short)bk;
                }
            }
            __syncthreads();
            // reserve global runs; sb[i] := gbase_i - lstart_i
            for (int i = t; i < NBd; i += 1024) {
                int c = hist[i];
                int g = c ? atomicAdd(&gd[i], c) : 0;
                sb[i] = g - (sa[i] - c);
            }
            __syncthreads();
            int total = sa[NBd - 1];
            // coalesced flush: consecutive i -> consecutive addresses per run
            for (int i = t; i < total; i += 1024) {
                int bk = bmap[i];
                int gpos = sb[bk] + i;
                if (gpos < CAPD) bd[(size_t)bk * CAPD + gpos] = stg[i];
            }
        }
        __syncthreads();

        // ================= phase B: src buckets (value = s&255, byte) ====
        for (int i = t; i < NBs; i += 1024) hist[i] = 0;
        __syncthreads();
#pragma unroll
        for (int k = 0; k < 8; ++k)
            if (se[k] >= 0) atomicAdd(&hist[se[k] >> 8], 1);
        __syncthreads();
        {
            int* sa = scanA;
            int* sb = scanB;
            for (int i = t; i < NBs; i += 1024) sa[i] = hist[i];
            __syncthreads();
            for (int off = 1; off < NBs; off <<= 1) {
                for (int i = t; i < NBs; i += 1024) {
                    int v = sa[i];
                    if (i >= off) v += sa[i - off];
                    sb[i] = v;
                }
                __syncthreads();
                int* tp = sa; sa = sb; sb = tp;
            }
            for (int i = t; i < NBs; i += 1024) sb[i] = sa[i] - hist[i];
            __syncthreads();
#pragma unroll
            for (int k = 0; k < 8; ++k) {
                if (se[k] >= 0) {
                    int bk = se[k] >> 8;
                    int p = atomicAdd(&sb[bk], 1);
                    stg[p] = (unsigned int)(se[k] & 255);
                    bmap[p] = (unsigned short)bk;
                }
            }
            __syncthreads();
            for (int i = t; i < NBs; i += 1024) {
                int c = hist[i];
                int g = c ? atomicAdd(&gs[i], c) : 0;
                sb[i] = g - (sa[i] - c);
            }
            __syncthreads();
            int total = sa[NBs - 1];
            for (int i = t; i < total; i += 1024) {
                int bk = bmap[i];
                int gpos = sb[bk] + i;
                if (gpos < CAPS) bs[(size_t)bk * CAPS + gpos] = (unsigned char)stg[i];
            }
        }
    } else if (b < A1 + A2 + B3) {
        // x fp32 -> bf16, 8 elems/thread, exact thread count. NT loads keep
        // the read-once x stream out of L2.
        size_t tid = (size_t)(b - A1 - A2) * 1024 + t;
        const f32x4* xp = (const f32x4*)x;
        f32x4 a = __builtin_nontemporal_load(xp + tid * 2);
        f32x4 c = __builtin_nontemporal_load(xp + tid * 2 + 1);
        u32x4 o;
        o.x = pack2(a.x, a.y);
        o.y = pack2(a.z, a.w);
        o.z = pack2(c.x, c.y);
        o.w = pack2(c.z, c.w);
        ((u32x4*)xn)[tid] = o;
    } else {
        int w = b - (A1 + A2 + B3);          // 0..63; 32 blocks per weight
        int which = w >> 5;
        const float* W = which ? W2 : W1;
        unsigned short* out = which ? Bp2 : Bp1;
        int N = which ? F3 : F2;
        int idx = (w & 31) * 1024 + t;       // both weights have 32768 elems
        int k = idx / N, n = idx % N;
        unsigned short v = f2bf(W[idx]);
        int kt = k >> 5, q = (k >> 3) & 3, j = k & 7;
        int nt = n >> 4, lane = q * 16 + (n & 15);
        int NT = N >> 4;
        out[(((kt * NT + nt) * 64 + lane) << 3) + j] = v;
    }
}

// ---------------------------------------------------------------- kernel B (1024 thr)
// one block per bucket. dst-buckets: padded CSR + cnt_in + rs_in.
// src-buckets: degree histogram -> rs_out.
__global__ __launch_bounds__(1024) void bucket_build(
    const int* __restrict__ gcnt,
    const unsigned int* __restrict__ bkt_d1, const unsigned int* __restrict__ bkt_d2,
    const unsigned char* __restrict__ bkt_s1, const unsigned char* __restrict__ bkt_s2,
    int* __restrict__ csr1, int* __restrict__ cnt_in1, float* __restrict__ rs_in1,
    int* __restrict__ csr2, int* __restrict__ cnt_in2, float* __restrict__ rs_in2,
    float* __restrict__ rs_out1, float* __restrict__ rs_out2) {
    __shared__ int hist[256];
    int b = blockIdx.x, t = threadIdx.x;
    if (t < 256) hist[t] = 0;
    __syncthreads();

    if (b < NB1D + NB2D) {
        const int L1 = (b < NB1D);
        int bb = L1 ? b : b - NB1D;
        const unsigned int* bkt = L1 ? bkt_d1 : bkt_d2;
        int* csr = L1 ? csr1 : csr2;
        int* cnt_in = L1 ? cnt_in1 : cnt_in2;
        float* rs_in = L1 ? rs_in1 : rs_in2;
        int Nd = L1 ? 100000 : 50000;
        int n = gcnt[(L1 ? GD1 : GD2) + bb];
        if (n > CAPD) n = CAPD;
        size_t base = (size_t)bb * CAPD;
        for (int i = t; i < n; i += 1024) {
            unsigned int v = bkt[base + i];
            int d = v & 255, s = (int)(v >> 8);
            int pos = atomicAdd(&hist[d], 1);
            if (pos < CAP) csr[((size_t)(bb * 256 + d)) * CAP + pos] = s;
        }
        __syncthreads();
        int node = bb * 256 + t;
        if (t < 256 && node < Nd) {
            int c = hist[t];
            cnt_in[node] = c < CAP ? c : CAP;
            rs_in[node] = rsqrtf((float)(c < 1 ? 1 : c));
        }
    } else {
        const int L1 = (b < NB1D + NB2D + NB1S);
        int bb = L1 ? b - (NB1D + NB2D) : b - (NB1D + NB2D + NB1S);
        const unsigned char* bkt = L1 ? bkt_s1 : bkt_s2;
        float* rs_out = L1 ? rs_out1 : rs_out2;
        int Ns = L1 ? 200000 : 100000;
        int n = gcnt[(L1 ? GS1 : GS2) + bb];
        if (n > CAPS) n = CAPS;
        size_t base = (size_t)bb * CAPS;
        for (int i = t; i < n; i += 1024) atomicAdd(&hist[bkt[base + i]], 1);
        __syncthreads();
        int node = bb * 256 + t;
        if (t < 256 && node < Ns) rs_out[node] = rsqrtf((float)(hist[t] < 1 ? 1 : hist[t]));
    }
}

// ---------------------------------------------------------------- gather aggregation
// F=128 bf16 rows, one wave per dst row. eg = lane>>4 picks one of 4 edges per
// group, fs = lane&15 picks a 16B feature slot. 16 edges/iteration = 4
// independent u32x4 row-gathers (blend-BW ceiling: 410 MB L2-side demand at
// ~6.1 TB/s aggregate). Packed f32x2 accumulation (v_pk_fma) cuts per-row
// VALU 16->12 ops to minimize co-issue overhead.
__global__ __launch_bounds__(256) void agg128_kernel(
    const unsigned int* __restrict__ X, const int* __restrict__ csr,
    const int* __restrict__ cnt, const float* __restrict__ rs_src,
    unsigned int* __restrict__ out, int ndst) {
    int wave = (int)((blockIdx.x * blockDim.x + threadIdx.x) >> 6);
    int lane = threadIdx.x & 63;
    if (wave >= ndst) return;
    size_t base = (size_t)wave * CAP;
    int len = cnt[wave];
    int sl = 0;
    float clv = 0.f;
    if (lane < len) {
        sl = csr[base + lane];
        clv = rs_src[sl];
    }
    int eg = lane >> 4, fs = lane & 15;
    f32x2 av[4];
#pragma unroll
    for (int i = 0; i < 4; ++i) av[i] = (f32x2){0.f, 0.f};
    for (int j = 0; j < len; j += 16) {
        int jA = j + eg, jB = j + 4 + eg, jC = j + 8 + eg, jD = j + 12 + eg;
        int sA = __shfl(sl, jA);
        int sB = __shfl(sl, jB);
        int sC = __shfl(sl, jC);
        int sD = __shfl(sl, jD);
        float cA = __shfl(clv, jA);
        float cB = __shfl(clv, jB);
        float cC = __shfl(clv, jC);
        float cD = __shfl(clv, jD);
        u32x4 uA = *(const u32x4*)(X + (size_t)sA * 64 + (fs << 2));
        u32x4 uB = *(const u32x4*)(X + (size_t)sB * 64 + (fs << 2));
        u32x4 uC = *(const u32x4*)(X + (size_t)sC * 64 + (fs << 2));
        u32x4 uD = *(const u32x4*)(X + (size_t)sD * 64 + (fs << 2));
        f32x2 ccA = (f32x2){cA, cA};
        f32x2 ccB = (f32x2){cB, cB};
        f32x2 ccC = (f32x2){cC, cC};
        f32x2 ccD = (f32x2){cD, cD};
        ACC_ROW2(uA, ccA)
        ACC_ROW2(uB, ccB)
        ACC_ROW2(uC, ccC)
        ACC_ROW2(uD, ccD)
    }
#pragma unroll
    for (int i = 0; i < 4; ++i) {
        av[i].x += __shfl_xor(av[i].x, 16);
        av[i].x += __shfl_xor(av[i].x, 32);
        av[i].y += __shfl_xor(av[i].y, 16);
        av[i].y += __shfl_xor(av[i].y, 32);
    }
    if (eg == 0) {
        u32x4 o;
        o.x = pack2(av[0].x, av[0].y);
        o.y = pack2(av[1].x, av[1].y);
        o.z = pack2(av[2].x, av[2].y);
        o.w = pack2(av[3].x, av[3].y);
        *((u32x4*)(out + (size_t)wave * 64) + fs) = o;
    }
}

// ---------------------------------------------------------------- fused two-stage GEMM
// 512 threads = 8 waves x 16 rows = 128-row tile. B matrices staged in LDS.
// T14 split: Bp2 global loads issued with phase 0 (held in regs through
// stage 1), LDS-written after the stage-1 barrier. Pad rows [M, YPAD) are
// written as ZEROS (agg_final sentinel rows).
__global__ __launch_bounds__(512) void gemm12(
    const unsigned short* __restrict__ A,    // agg [M,128] bf16
    const unsigned short* __restrict__ Bp1,  // W1 fragments (K=128,N=256)
    const unsigned short* __restrict__ Bp2,  // W2 fragments (K=256,N=128)
    const float* __restrict__ rs1, const float* __restrict__ rs2,
    const float* __restrict__ bias1,
    unsigned short* __restrict__ Y, int M) {
    __shared__ unsigned short Bs[32768];      // 64 KB, holds Bp1 then Bp2
    __shared__ unsigned short tmp[128][264];  // +8 pad, 67.6 KB
    int lane = threadIdx.x & 63, wid = threadIdx.x >> 6;
    int t = threadIdx.x;
    int row0 = blockIdx.x * 128 + wid * 16;
    int q = lane >> 4, col = lane & 15;

    // ---- phase 0: Bp1 -> LDS; Bp2 -> regs (issue-early, consume-late)
    u32x4 b2r[8];
#pragma unroll
    for (int i = 0; i < 8; ++i) {
        ((u32x4*)Bs)[i * 512 + t] = ((const u32x4*)Bp1)[i * 512 + t];
        b2r[i] = ((const u32x4*)Bp2)[i * 512 + t];
    }
    __syncthreads();

    // ---- stage 1: 16 rows x 256 cols per wave
    int mload = row0 + col;
    if (mload > M - 1) mload = M - 1;
    const unsigned short* Arow = A + (size_t)mload * F1 + q * 8;
    f32x4 acc[16];
#pragma unroll
    for (int i = 0; i < 16; ++i) acc[i] = (f32x4){0.f, 0.f, 0.f, 0.f};
#pragma unroll
    for (int kt = 0; kt < 4; ++kt) {
        bf16x8 a = *(const bf16x8*)(Arow + kt * 32);
#pragma unroll
        for (int nt = 0; nt < 16; ++nt) {
            bf16x8 bfr = *(const bf16x8*)(Bs + (((kt * 16 + nt) * 64 + lane) << 3));
            acc[nt] = __builtin_amdgcn_mfma_f32_16x16x32_bf16(a, bfr, acc[nt], 0, 0, 0);
        }
    }
#pragma unroll
    for (int r = 0; r < 4; ++r) {
        int lrow = wid * 16 + q * 4 + r;
        int m = row0 + q * 4 + r;
        int mc = m < M ? m : M - 1;
        float s1 = rs1[mc], s2 = rs2[mc];
#pragma unroll
        for (int nt = 0; nt < 16; ++nt) {
            float v = fmaxf(fmaf(acc[nt][r], s1, bias1[nt * 16 + col]), 0.f) * s2;
            tmp[lrow][nt * 16 + col] = f2bf(v);
        }
    }
    __syncthreads();

    // ---- phase 2: regs -> LDS (overwrite Bp1 region)
#pragma unroll
    for (int i = 0; i < 8; ++i)
        ((u32x4*)Bs)[i * 512 + t] = b2r[i];
    __syncthreads();

    // ---- stage 2: same 16 rows x 128 cols, K=256 from tmp
    f32x4 acc2[8];
#pragma unroll
    for (int i = 0; i < 8; ++i) acc2[i] = (f32x4){0.f, 0.f, 0.f, 0.f};
    const unsigned short* trow = &tmp[wid * 16 + col][q * 8];
#pragma unroll
    for (int kt = 0; kt < 8; ++kt) {
        bf16x8 a = *(const bf16x8*)(trow + kt * 32);
#pragma unroll
        for (int nt = 0; nt < 8; ++nt) {
            bf16x8 bfr = *(const bf16x8*)(Bs + (((kt * 8 + nt) * 64 + lane) << 3));
            acc2[nt] = __builtin_amdgcn_mfma_f32_16x16x32_bf16(a, bfr, acc2[nt], 0, 0, 0);
        }
    }
#pragma unroll
    for (int r = 0; r < 4; ++r) {
        int m = row0 + q * 4 + r;
        int live = m < M;
#pragma unroll
        for (int nt = 0; nt < 8; ++nt)
            Y[(size_t)m * F3 + nt * 16 + col] = live ? f2bf(acc2[nt][r]) : (unsigned short)0;
    }
}

// ---------------------------------------------------------------- final aggregation
// gather y rows (128 bf16), sum, out = relu(rs_in2[d]*sum + b2) -> fp32
// Dead lanes point at the zero sentinel row (zrow) -> unconditional packed adds.
__global__ __launch_bounds__(256) void agg_final(
    const unsigned int* __restrict__ Yv, const int* __restrict__ csr,
    const int* __restrict__ cnt, const float* __restrict__ rs_dst,
    const float* __restrict__ b2, float* __restrict__ out, int ndst, int zrow) {
    int wave = (int)((blockIdx.x * blockDim.x + threadIdx.x) >> 6);
    int lane = threadIdx.x & 63;
    if (wave >= ndst) return;
    size_t base = (size_t)wave * CAP;
    int len = cnt[wave];
    int sl = zrow;
    if (lane < len) sl = csr[base + lane];
    int eg = lane >> 4, fs = lane & 15;
    f32x2 av[4];
#pragma unroll
    for (int i = 0; i < 4; ++i) av[i] = (f32x2){0.f, 0.f};
    for (int j = 0; j < len; j += 16) {
        int jA = j + eg, jB = j + 4 + eg, jC = j + 8 + eg, jD = j + 12 + eg;
        int sA = __shfl(sl, jA);
        int sB = __shfl(sl, jB);
        int sC = __shfl(sl, jC);
        int sD = __shfl(sl, jD);
        u32x4 uA = *(const u32x4*)(Yv + (size_t)sA * 64 + (fs << 2));
        u32x4 uB = *(const u32x4*)(Yv + (size_t)sB * 64 + (fs << 2));
        u32x4 uC = *(const u32x4*)(Yv + (size_t)sC * 64 + (fs << 2));
        u32x4 uD = *(const u32x4*)(Yv + (size_t)sD * 64 + (fs << 2));
        ACC_ROW_ADD2(uA)
        ACC_ROW_ADD2(uB)
        ACC_ROW_ADD2(uC)
        ACC_ROW_ADD2(uD)
    }
#pragma unroll
    for (int i = 0; i < 4; ++i) {
        av[i].x += __shfl_xor(av[i].x, 16);
        av[i].x += __shfl_xor(av[i].x, 32);
        av[i].y += __shfl_xor(av[i].y, 16);
        av[i].y += __shfl_xor(av[i].y, 32);
    }
    if (eg < 2) {
        float sc = rs_dst[wave];
        f32x4 bias = ((const f32x4*)b2)[(fs << 1) | eg];
        // static-index selection (no runtime-indexed register array)
        float v0 = eg ? av[2].x : av[0].x;
        float v1 = eg ? av[2].y : av[0].y;
        float v2 = eg ? av[3].x : av[1].x;
        float v3 = eg ? av[3].y : av[1].y;
        f32x4 o;
        o.x = fmaxf(fmaf(v0, sc, bias.x), 0.f);
        o.y = fmaxf(fmaf(v1, sc, bias.y), 0.f);
        o.z = fmaxf(fmaf(v2, sc, bias.z), 0.f);
        o.w = fmaxf(fmaf(v3, sc, bias.w), 0.f);
        __builtin_nontemporal_store(o, (f32x4*)out + (size_t)wave * 32 + (fs << 1) + eg);
    }
}

extern "C" void kernel_launch(void* const* d_in, const int* in_sizes, int n_in,
                              void* d_out, int out_size, void* d_ws, size_t ws_size,
                              hipStream_t stream) {
    const float* x  = (const float*)d_in[0];
    const float* W1 = (const float*)d_in[1];
    const float* b1 = (const float*)d_in[2];
    const float* W2 = (const float*)d_in[3];
    const float* b2 = (const float*)d_in[4];
    const int* src1 = (const int*)d_in[5];
    const int* dst1 = (const int*)d_in[6];
    const int* src2 = (const int*)d_in[7];
    const int* dst2 = (const int*)d_in[8];
    const int E1 = in_sizes[5], E2 = in_sizes[7];
    const int N0 = in_sizes[0] / F1;  // 200000
    const int N1 = 100000, N2 = 50000;

    // ---- workspace layout (all segment sizes multiples of 16 B)
    char* p = (char*)d_ws;
    int* gcnt = (int*)p; p += 2048 * 4;                          // 1760 used
    float* rs_out1 = (float*)p; p += (size_t)N0 * 4;
    float* rs_in1  = (float*)p; p += (size_t)N1 * 4;
    float* rs_out2 = (float*)p; p += (size_t)N1 * 4;
    float* rs_in2  = (float*)p; p += (size_t)N2 * 4;
    int* cnt_in1 = (int*)p; p += (size_t)N1 * 4;
    int* cnt_in2 = (int*)p; p += (size_t)N2 * 4;
    unsigned int* bkt_d1 = (unsigned int*)p; p += (size_t)NB1D * CAPD * 4;  // 7.2 MB
    unsigned int* bkt_d2 = (unsigned int*)p; p += (size_t)NB2D * CAPD * 4;  // 3.6 MB
    unsigned char* bkt_s1 = (unsigned char*)p; p += (size_t)NB1S * CAPS;    // 1.9 MB
    unsigned char* bkt_s2 = (unsigned char*)p; p += (size_t)NB2S * CAPS;    // 1.0 MB
    int* csr1 = (int*)p; p += (size_t)N1 * CAP * 4;              // 25.6 MB
    int* csr2 = (int*)p; p += (size_t)N2 * CAP * 4;              // 12.8 MB
    unsigned short* Bp1 = (unsigned short*)p; p += (size_t)F1 * F2 * 2;
    unsigned short* Bp2 = (unsigned short*)p; p += (size_t)F2 * F3 * 2;
    unsigned short* xn  = (unsigned short*)p; p += (size_t)N0 * F1 * 2;  // 51.2 MB
    unsigned short* agg = (unsigned short*)p; p += (size_t)N1 * F1 * 2;  // 25.6 MB
    // y aliases xn: xn dead after agg128; y (YPAD*F3 elems incl. zero pad rows)
    unsigned short* y = xn;

    (void)hipMemsetAsync(gcnt, 0, 2048 * 4, stream);

    // kernel A: bucket scatter (both layers) + x->bf16 + weight permutes
    int A1 = (E1 + 8191) / 8192;
    int A2 = (E2 + 8191) / 8192;
    int B3 = N0 * F1 / 8 / 1024;  // exact: 3125
    scatter_build<<<A1 + A2 + B3 + 64, 1024, 0, stream>>>(
        src1, dst1, src2, dst2, x, W1, W2, gcnt,
        bkt_d1, bkt_d2, bkt_s1, bkt_s2,
        (unsigned int*)xn, Bp1, Bp2, E1, E2, A1, A2, B3);

    // kernel B: per-bucket CSR + degree norms
    bucket_build<<<NB1D + NB2D + NB1S + NB2S, 1024, 0, stream>>>(
        gcnt, bkt_d1, bkt_d2, bkt_s1, bkt_s2,
        csr1, cnt_in1, rs_in1, csr2, cnt_in2, rs_in2, rs_out1, rs_out2);

    // layer 1 aggregation (per-edge src norm)
    agg128_kernel<<<(N1 + 3) / 4, 256, 0, stream>>>((const unsigned int*)xn, csr1,
                                                    cnt_in1, rs_out1,
                                                    (unsigned int*)agg, N1);

    // fused: hn = relu(rs_in1*(agg@W1)+b1)*rs_out2 ; y = hn@W2  (+ zero pads)
    gemm12<<<(N1 + 127) / 128, 512, 0, stream>>>(agg, Bp1, Bp2, rs_in1, rs_out2, b1, y, N1);

    // layer 2 aggregation + fused epilogue: out = relu(rs_in2*segsum(y) + b2)
    agg_final<<<(N2 + 3) / 4, 256, 0, stream>>>((const unsigned int*)y, csr2, cnt_in2,
                                                rs_in2, b2, (float*)d_out, N2, N1);
}